// Round 1
// baseline (448.185 us; speedup 1.0000x reference)
//
#include <hip/hip_runtime.h>

#define DEVFN __device__ __forceinline__

typedef __bf16 bf16x8 __attribute__((ext_vector_type(8)));
typedef float f32x4 __attribute__((ext_vector_type(4)));
typedef unsigned short u16;

// constants for this problem
// B=2, T=S=2048, D=1024, H=16, DH=64

DEVFN u16 f2bf(float f) {
  unsigned u = __builtin_bit_cast(unsigned, f);
  u += 0x7FFFu + ((u >> 16) & 1u);
  return (u16)(u >> 16);
}

DEVFN f32x4 mfma16(bf16x8 a, bf16x8 b, f32x4 c) {
  return __builtin_amdgcn_mfma_f32_16x16x32_bf16(a, b, c, 0, 0, 0);
}

// ---------------- LayerNorm: x[4096,1024] -> xn (f32, into d_out) + xn bf16 ----------------
__global__ __launch_bounds__(256) void ln_kernel(const float* __restrict__ x,
                                                 const float* __restrict__ gamma,
                                                 const float* __restrict__ beta,
                                                 float* __restrict__ xn,
                                                 u16* __restrict__ xnb) {
  int row = blockIdx.x;
  int tid = threadIdx.x;
  const float4* xr = (const float4*)(x + (size_t)row * 1024);
  float4 v = xr[tid];
  float s = v.x + v.y + v.z + v.w;
  float q = v.x * v.x + v.y * v.y + v.z * v.z + v.w * v.w;
#pragma unroll
  for (int m = 1; m < 64; m <<= 1) {
    s += __shfl_xor(s, m);
    q += __shfl_xor(q, m);
  }
  __shared__ float rs[4], rq[4];
  int w = tid >> 6;
  if ((tid & 63) == 0) { rs[w] = s; rq[w] = q; }
  __syncthreads();
  s = rs[0] + rs[1] + rs[2] + rs[3];
  q = rq[0] + rq[1] + rq[2] + rq[3];
  float mean = s * (1.0f / 1024.0f);
  float var = q * (1.0f / 1024.0f) - mean * mean;
  float inv = rsqrtf(var + 1e-5f);
  float4 g = ((const float4*)gamma)[tid];
  float4 bt = ((const float4*)beta)[tid];
  float4 o;
  o.x = (v.x - mean) * inv * g.x + bt.x;
  o.y = (v.y - mean) * inv * g.y + bt.y;
  o.z = (v.z - mean) * inv * g.z + bt.z;
  o.w = (v.w - mean) * inv * g.w + bt.w;
  ((float4*)(xn + (size_t)row * 1024))[tid] = o;
  ushort4 ob;
  ob.x = f2bf(o.x); ob.y = f2bf(o.y); ob.z = f2bf(o.z); ob.w = f2bf(o.w);
  ((ushort4*)(xnb + (size_t)row * 1024))[tid] = ob;
}

// ---------------- f32 -> bf16 convert (vectorized by 4) ----------------
__global__ __launch_bounds__(256) void cvt_kernel(const float* __restrict__ in,
                                                  u16* __restrict__ out, int n4) {
  int i = blockIdx.x * 256 + threadIdx.x;
  if (i < n4) {
    float4 v = ((const float4*)in)[i];
    ushort4 o;
    o.x = f2bf(v.x); o.y = f2bf(v.y); o.z = f2bf(v.z); o.w = f2bf(v.w);
    ((ushort4*)out)[i] = o;
  }
}

// ---------------- W [1024,1024] f32 -> Wt [1024,1024] bf16 transposed ----------------
__global__ __launch_bounds__(256) void transW_kernel(const float* __restrict__ W,
                                                     u16* __restrict__ Wt) {
  __shared__ float tile[32][33];
  int tx = threadIdx.x, ty = threadIdx.y;
  int x = blockIdx.x * 32 + tx;   // col n of W
  int y0 = blockIdx.y * 32;       // row k base
#pragma unroll
  for (int j = 0; j < 32; j += 8)
    tile[ty + j][tx] = W[(size_t)(y0 + ty + j) * 1024 + x];
  __syncthreads();
#pragma unroll
  for (int j = 0; j < 32; j += 8)
    Wt[(size_t)(blockIdx.x * 32 + ty + j) * 1024 + y0 + tx] = f2bf(tile[tx][ty + j]);
}

// ---------------- 128x128 GEMM, K=1024, bf16 in / MFMA ----------------
// A [M,1024] bf16 row-major; Bt [1024,1024] bf16 (N-major, i.e. B transposed).
// MODE 0: write bf16 to [B,H,2048,64] layout. MODE 1: f32 out = acc + bias[n] + resid[m,n].
template <int MODE>
__global__ __launch_bounds__(256, 2) void gemm128_kernel(
    const u16* __restrict__ A, const u16* __restrict__ Bt,
    u16* __restrict__ outB, const float* __restrict__ bias,
    const float* __restrict__ resid, float* __restrict__ outF) {
  constexpr int K = 1024;
  __shared__ u16 Ab[128 * 72];
  __shared__ u16 Bb[128 * 72];
  int tid = threadIdx.x;
  int lane = tid & 63, wv = tid >> 6;
  int l16 = lane & 15, lhi = lane >> 4;
  int wr = wv >> 1, wc = wv & 1;
  int row0 = blockIdx.x * 128, n0 = blockIdx.y * 128;

  uint4 ra[4], rb[4];
  auto loadtile = [&](int k0) {
#pragma unroll
    for (int i = 0; i < 4; ++i) {
      int sl = i * 256 + tid, r = sl >> 3, c = sl & 7;
      ra[i] = *(const uint4*)&A[(size_t)(row0 + r) * K + k0 + c * 8];
      rb[i] = *(const uint4*)&Bt[(size_t)(n0 + r) * K + k0 + c * 8];
    }
  };
  auto writetile = [&]() {
#pragma unroll
    for (int i = 0; i < 4; ++i) {
      int sl = i * 256 + tid, r = sl >> 3, c = sl & 7;
      *(uint4*)&Ab[r * 72 + c * 8] = ra[i];
      *(uint4*)&Bb[r * 72 + c * 8] = rb[i];
    }
  };

  f32x4 acc[4][4] = {};
  loadtile(0);
  writetile();
  __syncthreads();
  for (int kk = 0; kk < 16; ++kk) {
    if (kk + 1 < 16) loadtile((kk + 1) * 64);
#pragma unroll
    for (int ks = 0; ks < 2; ++ks) {
      bf16x8 af[4], bfr[4];
#pragma unroll
      for (int mi = 0; mi < 4; ++mi)
        af[mi] = *(const bf16x8*)&Ab[(wr * 64 + mi * 16 + l16) * 72 + ks * 32 + lhi * 8];
#pragma unroll
      for (int ni = 0; ni < 4; ++ni)
        bfr[ni] = *(const bf16x8*)&Bb[(wc * 64 + ni * 16 + l16) * 72 + ks * 32 + lhi * 8];
#pragma unroll
      for (int mi = 0; mi < 4; ++mi)
#pragma unroll
        for (int ni = 0; ni < 4; ++ni)
          acc[mi][ni] = mfma16(af[mi], bfr[ni], acc[mi][ni]);
    }
    __syncthreads();
    if (kk + 1 < 16) writetile();
    __syncthreads();
  }

#pragma unroll
  for (int mi = 0; mi < 4; ++mi)
#pragma unroll
    for (int ni = 0; ni < 4; ++ni)
#pragma unroll
      for (int r = 0; r < 4; ++r) {
        int m = row0 + wr * 64 + mi * 16 + lhi * 4 + r;
        int n = n0 + wc * 64 + ni * 16 + l16;
        float val = acc[mi][ni][r];
        if (MODE == 0) {
          int b = m >> 11, t = m & 2047, h = n >> 6, dh = n & 63;
          outB[(size_t)((b * 16 + h) * 2048 + t) * 64 + dh] = f2bf(val);
        } else {
          val += bias[n] + resid[(size_t)m * 1024 + n];
          outF[(size_t)m * 1024 + n] = val;
        }
      }
}

// ---------------- flash attention with relative-position band ----------------
// Q,K,V: [B,H,2048,64] bf16. Lb: [4095,64] bf16. Og: [B*T, 1024] bf16.
__global__ __launch_bounds__(256, 2) void flash_kernel(
    const u16* __restrict__ Qg, const u16* __restrict__ Kg,
    const u16* __restrict__ Vg, const u16* __restrict__ Lb,
    u16* __restrict__ Og) {
  constexpr int T = 2048, S = 2048, H = 16;
  int bid = blockIdx.x;
  int qb = bid & 31, h = (bid >> 5) & 15, b = bid >> 9;
  int tid = threadIdx.x;
  int lane = tid & 63, w = tid >> 6;
  int l16 = lane & 15, lhi = lane >> 4;

  __shared__ u16 Klds[64 * 72];
  __shared__ u16 Vt[64 * 72];
  __shared__ float Elds[4][16 * 81];
  __shared__ u16 Plds[4][16 * 72];

  const u16* qbase = Qg + (size_t)(b * H + h) * T * 64;
  const u16* kbase = Kg + (size_t)(b * H + h) * S * 64;
  const u16* vbase = Vg + (size_t)(b * H + h) * S * 64;

  int i0w = qb * 64 + w * 16;  // this wave's first query row
  bf16x8 aq[2];
  aq[0] = *(const bf16x8*)&qbase[(i0w + l16) * 64 + lhi * 8];
  aq[1] = *(const bf16x8*)&qbase[(i0w + l16) * 64 + 32 + lhi * 8];

  f32x4 accO[4] = {};
  float mrun[4], lrun[4];
#pragma unroll
  for (int r = 0; r < 4; ++r) { mrun[r] = -1e30f; lrun[r] = 0.0f; }

  int bandbase = T - 16 - i0w;  // bstart = bandbase + j0 ; u = bstart + colE

  for (int kt = 0; kt < 32; ++kt) {
    int j0 = kt * 64;
    // stage K tile [64 keys][64 d] (stride 72)
#pragma unroll
    for (int i = 0; i < 2; ++i) {
      int sl = i * 256 + tid, key = sl >> 3, c = sl & 7;
      *(uint4*)&Klds[key * 72 + c * 8] = *(const uint4*)&kbase[(size_t)(j0 + key) * 64 + c * 8];
    }
    // stage V^T tile [64 d][64 keys] (stride 72)
    {
      int p = tid & 31, d0 = (tid >> 5) * 8;
      uint4 r0 = *(const uint4*)&vbase[(size_t)(j0 + 2 * p) * 64 + d0];
      uint4 r1 = *(const uint4*)&vbase[(size_t)(j0 + 2 * p + 1) * 64 + d0];
      const u16* s0 = (const u16*)&r0;
      const u16* s1 = (const u16*)&r1;
#pragma unroll
      for (int i = 0; i < 8; ++i) {
        ushort2 pr; pr.x = s0[i]; pr.y = s1[i];
        *(ushort2*)&Vt[(d0 + i) * 72 + 2 * p] = pr;
      }
    }
    __syncthreads();

    // QK^T : accS[kb][r] = S[m = lhi*4+r][n = kb*16+l16]
    f32x4 accS[4] = {};
#pragma unroll
    for (int ks = 0; ks < 2; ++ks)
#pragma unroll
      for (int kb2 = 0; kb2 < 4; ++kb2) {
        bf16x8 bk = *(const bf16x8*)&Klds[(kb2 * 16 + l16) * 72 + ks * 32 + lhi * 8];
        accS[kb2] = mfma16(aq[ks], bk, accS[kb2]);
      }

    // E = Q @ L_band^T   (band of 79 rows, padded to 80)
    f32x4 accE[5] = {};
    int bstart = bandbase + j0;
#pragma unroll
    for (int ks = 0; ks < 2; ++ks)
#pragma unroll
      for (int c = 0; c < 5; ++c) {
        int u = bstart + c * 16 + l16;
        u = min(max(u, 0), 2 * T - 2);
        bf16x8 bl = *(const bf16x8*)&Lb[(size_t)u * 64 + ks * 32 + lhi * 8];
        accE[c] = mfma16(aq[ks], bl, accE[c]);
      }
    // spill E to LDS for the skewed gather
#pragma unroll
    for (int c = 0; c < 5; ++c)
#pragma unroll
      for (int r = 0; r < 4; ++r)
        Elds[w][(lhi * 4 + r) * 81 + c * 16 + l16] = accE[c][r];
    asm volatile("s_waitcnt lgkmcnt(0)" ::: "memory");

    // scores + online softmax; P -> LDS (bf16)
#pragma unroll
    for (int r = 0; r < 4; ++r) {
      int m = lhi * 4 + r;
      float sc[4];
#pragma unroll
      for (int kb2 = 0; kb2 < 4; ++kb2) {
        int col = kb2 * 16 + l16 - m + 15;  // in [0,78]
        sc[kb2] = accS[kb2][r] * (1.0f / 64.0f) + Elds[w][m * 81 + col] * 0.125f;
      }
      float tm = fmaxf(fmaxf(sc[0], sc[1]), fmaxf(sc[2], sc[3]));
      tm = fmaxf(tm, __shfl_xor(tm, 1));
      tm = fmaxf(tm, __shfl_xor(tm, 2));
      tm = fmaxf(tm, __shfl_xor(tm, 4));
      tm = fmaxf(tm, __shfl_xor(tm, 8));
      float mnew = fmaxf(mrun[r], tm);
      float alpha = __expf(mrun[r] - mnew);
      mrun[r] = mnew;
      float ls = 0.0f;
#pragma unroll
      for (int kb2 = 0; kb2 < 4; ++kb2) {
        float p = __expf(sc[kb2] - mnew);
        ls += p;
        Plds[w][m * 72 + kb2 * 16 + l16] = f2bf(p);
      }
      ls += __shfl_xor(ls, 1);
      ls += __shfl_xor(ls, 2);
      ls += __shfl_xor(ls, 4);
      ls += __shfl_xor(ls, 8);
      lrun[r] = lrun[r] * alpha + ls;
#pragma unroll
      for (int dt = 0; dt < 4; ++dt) accO[dt][r] *= alpha;
    }
    asm volatile("s_waitcnt lgkmcnt(0)" ::: "memory");

    // PV: accO[dt] += P[16,64] @ V[64, dt*16..]
#pragma unroll
    for (int ks = 0; ks < 2; ++ks) {
      bf16x8 ap = *(const bf16x8*)&Plds[w][l16 * 72 + ks * 32 + lhi * 8];
#pragma unroll
      for (int dt = 0; dt < 4; ++dt) {
        bf16x8 bv = *(const bf16x8*)&Vt[(dt * 16 + l16) * 72 + ks * 32 + lhi * 8];
        accO[dt] = mfma16(ap, bv, accO[dt]);
      }
    }
    __syncthreads();
  }

  // epilogue: O /= l, write bf16 to [B*T, H*64]
#pragma unroll
  for (int dt = 0; dt < 4; ++dt)
#pragma unroll
    for (int r = 0; r < 4; ++r) {
      int i = i0w + lhi * 4 + r;
      int col = h * 64 + dt * 16 + l16;
      Og[(size_t)(b * T + i) * 1024 + col] = f2bf(accO[dt][r] / lrun[r]);
    }
}

extern "C" void kernel_launch(void* const* d_in, const int* in_sizes, int n_in,
                              void* d_out, int out_size, void* d_ws, size_t ws_size,
                              hipStream_t stream) {
  const float* x = (const float*)d_in[0];
  const float* ctx = (const float*)d_in[1];
  const float* Ltab = (const float*)d_in[2];
  const float* Wq = (const float*)d_in[3];
  const float* Wk = (const float*)d_in[4];
  const float* Wv = (const float*)d_in[5];
  const float* Wo = (const float*)d_in[6];
  const float* bo = (const float*)d_in[7];
  const float* gamma = (const float*)d_in[8];
  const float* beta = (const float*)d_in[9];
  float* out = (float*)d_out;

  size_t off = 0;
  auto take = [&](size_t bytes) {
    void* p = (char*)d_ws + off;
    off += (bytes + 255) & ~(size_t)255;
    return p;
  };
  u16* xnb = (u16*)take(8388608);     // xn bf16 [4096,1024]
  u16* ctxb = (u16*)take(8388608);    // context bf16
  u16* Lb = (u16*)take(4095 * 64 * 2);
  u16* Wqt = (u16*)take(2097152);
  u16* Wkt = (u16*)take(2097152);
  u16* Wvt = (u16*)take(2097152);
  u16* Wot = (u16*)take(2097152);
  u16* qbuf = (u16*)take(8388608);    // [B,H,T,64]
  u16* kbuf = (u16*)take(8388608);
  u16* vbuf = (u16*)take(8388608);
  u16* attnb = (u16*)take(8388608);   // [B*T, 1024]

  // 1) LayerNorm (xn f32 goes into d_out as the residual buffer)
  ln_kernel<<<dim3(4096), dim3(256), 0, stream>>>(x, gamma, beta, out, xnb);
  // 2) converts
  cvt_kernel<<<dim3(4096), dim3(256), 0, stream>>>(ctx, ctxb, 1048576);
  cvt_kernel<<<dim3(256), dim3(256), 0, stream>>>(Ltab, Lb, 65520);
  // 3) weight transposes (f32 -> bf16, N-major)
  transW_kernel<<<dim3(32, 32), dim3(32, 8), 0, stream>>>(Wq, Wqt);
  transW_kernel<<<dim3(32, 32), dim3(32, 8), 0, stream>>>(Wk, Wkt);
  transW_kernel<<<dim3(32, 32), dim3(32, 8), 0, stream>>>(Wv, Wvt);
  transW_kernel<<<dim3(32, 32), dim3(32, 8), 0, stream>>>(Wo, Wot);
  // 4) projections
  gemm128_kernel<0><<<dim3(32, 8), dim3(256), 0, stream>>>(xnb, Wqt, qbuf, nullptr, nullptr, nullptr);
  gemm128_kernel<0><<<dim3(32, 8), dim3(256), 0, stream>>>(ctxb, Wkt, kbuf, nullptr, nullptr, nullptr);
  gemm128_kernel<0><<<dim3(32, 8), dim3(256), 0, stream>>>(ctxb, Wvt, vbuf, nullptr, nullptr, nullptr);
  // 5) attention with relative positions
  flash_kernel<<<dim3(1024), dim3(256), 0, stream>>>(qbuf, kbuf, vbuf, Lb, attnb);
  // 6) output projection + bias + residual (reads xn from d_out, writes final to d_out)
  gemm128_kernel<1><<<dim3(32, 8), dim3(256), 0, stream>>>(attnb, Wot, nullptr, bo, out, out);
}